// Round 5
// baseline (228.703 us; speedup 1.0000x reference)
//
#include <hip/hip_runtime.h>

#define ORDER 1024
#define NCOEF 1025
#define BATCH 8192

typedef float v2 __attribute__((ext_vector_type(2)));
typedef float v4f __attribute__((ext_vector_type(4)));

// lane i reads lane i-1; lane 0 reads 0 (bound_ctrl). Single VALU instr.
__device__ __forceinline__ float wave_shr1(float v) {
    int r = __builtin_amdgcn_update_dpp(0, __float_as_int(v),
                                        0x138 /*wave_shr:1*/, 0xf, 0xf, true);
    return __int_as_float(r);
}

// readfirstlane is int(int): bitcast round-trip, NOT value conversion.
__device__ __forceinline__ float sgpr_f32(float v) {
    return __int_as_float(__builtin_amdgcn_readfirstlane(__float_as_int(v)));
}

// Lane-local coefficient bank, stride-9 pairing on the 17-coeff cycle:
//   p[m] = (c_m, c_{m+9})  for m=0..7 ; x = (dpp scratch = c_{-1}, c_8)
// Shift-by-1 source of p[m] is p[m-1] (aligned -> v_pk_fma_f32).
struct Bank { v2 p[8]; v2 x; };

// One root step: B = A + nx * shift1(A). Ping-pong A<->B, no hazards.
__device__ __forceinline__ void step(Bank& A, Bank& B, float nx) {
    v2 nxp; nxp.x = nx; nxp.y = nx;
    A.x.x = wave_shr1(A.p[7].y);                   // c_{-1} = prev lane's c_16
    B.x.y = __builtin_fmaf(nx, A.p[7].x, A.x.y);   // c_8' = c_8 + nx*c_7
    B.p[0] = __builtin_elementwise_fma(nxp, A.x, A.p[0]);
#pragma unroll
    for (int m = 1; m < 8; ++m)
        B.p[m] = __builtin_elementwise_fma(nxp, A.p[m - 1], A.p[m]);
}

__global__ __launch_bounds__(256) void r2p_kernel(const float* __restrict__ x,
                                                  float* __restrict__ out) {
    const int wave = threadIdx.x >> 6;
    const int lane = threadIdx.x & 63;
    int row = (int)blockIdx.x * 4 + wave;
    row = __builtin_amdgcn_readfirstlane(row);

    const float* __restrict__ xr = x + (size_t)row * ORDER;
    float* __restrict__ orow = out + (size_t)row * NCOEF;

    Bank A, B;
#pragma unroll
    for (int m = 0; m < 8; ++m) {
        A.p[m].x = 0.0f; A.p[m].y = 0.0f;
        B.p[m].x = 0.0f; B.p[m].y = 0.0f;
    }
    A.x.x = 0.0f; A.x.y = 0.0f; B.x.x = 0.0f; B.x.y = 0.0f;
    if (lane == 0) A.p[0].x = 1.0f;   // c_0 = 1: empty product

    // Software-pipelined root stream: dwordx4 load issued one full
    // iteration (4 steps ~ 160 cyc of own work) ahead of first use, so the
    // cold-HBM miss (~900 cyc) is covered by own work + 7 co-resident waves.
    v4f xv = *(const v4f*)(xr);
    for (int i = 0; i < ORDER; i += 4) {
        const int nexti = (i + 4 < ORDER) ? i + 4 : i;  // uniform, SALU
        v4f xn = *(const v4f*)(xr + nexti);             // prefetch next group

        step(A, B, -sgpr_f32(xv.x));
        step(B, A, -sgpr_f32(xv.y));
        step(A, B, -sgpr_f32(xv.z));
        step(B, A, -sgpr_f32(xv.w));   // 4 steps (even) -> result back in A

        xv = xn;
    }

    // Store: k = 17*lane + j ; j=0..7 -> p[j].lo, j=8 -> x.hi, j=9..16 -> p[j-9].hi
#pragma unroll
    for (int j = 0; j < 8; ++j) {
        const int k = lane * 17 + j;
        if (k < NCOEF) orow[k] = A.p[j].x;
    }
    {
        const int k = lane * 17 + 8;
        if (k < NCOEF) orow[k] = A.x.y;
    }
#pragma unroll
    for (int j = 9; j < 17; ++j) {
        const int k = lane * 17 + j;
        if (k < NCOEF) orow[k] = A.p[j - 9].y;
    }
}

extern "C" void kernel_launch(void* const* d_in, const int* in_sizes, int n_in,
                              void* d_out, int out_size, void* d_ws, size_t ws_size,
                              hipStream_t stream) {
    const float* x = (const float*)d_in[0];
    float* out = (float*)d_out;
    dim3 grid(BATCH / 4);  // 4 waves (rows) per 256-thread block
    dim3 block(256);
    hipLaunchKernelGGL(r2p_kernel, grid, block, 0, stream, x, out);
}